// Round 4
// baseline (120.459 us; speedup 1.0000x reference)
//
#include <hip/hip_runtime.h>
#include <stdint.h>

// Encoder: B=2,E=512,T=2048,H=8,dh=64, local window |i-j|<=64
// R12: identical to R11 (unmeasured — GPU acquisition timeout). Audit found
//     no correctness defects. Known theoretical issue: BK=64 makes fragment
//     ds_read_b128 16-way bank-conflicted (128B row stride), but m252 shows
//     this is timing-null (+2%) at a 2-phase stage/drain structure; swizzle
//     deferred until counters show it matters.
// R11: - k_gemm_qkv: 128x96 tile, grid 512 (exactly 2 balanced blocks/CU,
//       was 384 => 2-vs-1 imbalance), BK 32->64 (8 drain steps, was 16).
//     - k_gemm_out: 64x64 tile, grid 512 (2+ blocks/CU co-resident for
//       drain overlap; was 256 @ 1/CU), BK 32->64.
//     - k_prep: 64x64 tiles, float4 loads + ushort4 stores.
//     - k_attention: R9 barrier-free structure (harness-verified).

#define DEVI __device__ __forceinline__

typedef __attribute__((ext_vector_type(8))) short bf16x8;   // 8 bf16 in 4 VGPRs
typedef __attribute__((ext_vector_type(4))) float f32x4;

DEVI unsigned short f2bf(float f) {               // RNE float->bf16
  unsigned u = __float_as_uint(f);
  u += 0x7fffu + ((u >> 16) & 1u);
  return (unsigned short)(u >> 16);
}
DEVI float bf2f(unsigned short h) { return __uint_as_float(((unsigned)h) << 16); }

#define GLL16(gp, lp)                                                          \
  __builtin_amdgcn_global_load_lds(                                            \
      (const __attribute__((address_space(1))) void*)(gp),                     \
      (__attribute__((address_space(3))) void*)(lp), 16, 0, 0)

#define MFMA(a, b, c) __builtin_amdgcn_mfma_f32_16x16x32_bf16((a), (b), (c), 0, 0, 0)

// ---------------------------------------------------------------------------
// K0: blockIdx.y<8: x[B,E,T] fp32 -> xT[B*T,512] bf16 (64x64 transpose tiles)
//     blockIdx.y==8: w_in/w_out fp32 -> bf16 (64 rider blocks x 16384 elems)
__global__ __launch_bounds__(256) void k_prep(
    const float* __restrict__ x, const float* __restrict__ w_in,
    const float* __restrict__ w_out, unsigned short* __restrict__ xh,
    unsigned short* __restrict__ wih, unsigned short* __restrict__ woh) {
  const int tid = threadIdx.x;
  if (blockIdx.y == 8) {  // weight convert rider
    int cb = (blockIdx.z << 5) | blockIdx.x;   // 0..63
    const float* src;
    unsigned short* dst;
    int base;
    if (cb < 48) {        // 48*16384 = 786432 = w_in exactly
      src = w_in; dst = wih; base = cb * 16384;
    } else {              // 16*16384 = 262144 = w_out exactly
      src = w_out; dst = woh; base = (cb - 48) * 16384;
    }
#pragma unroll
    for (int k = 0; k < 16; k++) {
      int idx = base + (k * 256 + tid) * 4;
      float4 v = *(const float4*)&src[idx];
      ushort4 o;
      o.x = f2bf(v.x); o.y = f2bf(v.y); o.z = f2bf(v.z); o.w = f2bf(v.w);
      *(ushort4*)&dst[idx] = o;
    }
    return;
  }
  __shared__ float tile[64][65];   // 16.6 KB
  const int b = blockIdx.z, e0 = blockIdx.y * 64, t0 = blockIdx.x * 64;
  const int g = tid >> 4, c4 = (tid & 15) * 4;   // g: 0..15
#pragma unroll
  for (int p = 0; p < 4; p++) {
    int el = p * 16 + g;
    float4 v = *(const float4*)&x[((size_t)b * 512 + e0 + el) * 2048 + t0 + c4];
    tile[el][c4 + 0] = v.x; tile[el][c4 + 1] = v.y;
    tile[el][c4 + 2] = v.z; tile[el][c4 + 3] = v.w;
  }
  __syncthreads();
#pragma unroll
  for (int p = 0; p < 4; p++) {
    int tl = p * 16 + g;
    ushort4 o;
    o.x = f2bf(tile[c4 + 0][tl]);
    o.y = f2bf(tile[c4 + 1][tl]);
    o.z = f2bf(tile[c4 + 2][tl]);
    o.w = f2bf(tile[c4 + 3][tl]);
    *(ushort4*)&xh[((size_t)(b * 2048 + t0 + tl)) * 512 + e0 + c4] = o;
  }
}

// ---------------------------------------------------------------------------
// QKV GEMM: C[m,n] = sum_k Ah[m,k]*Bh[n,k] + bias[n].
// Tile 128m x 96n, BK=64, grid 512 (32m x 16n), XCD-swizzled: exactly
// 2 balanced blocks/CU. Staging: 28 x 1KB chunks (A 16, B 12), 7/wave.
// Epilogue: Q(*0.125)/K -> [B,H,T,64] bf16, V -> [B,H,64,T] bf16 (ushort4).
__global__ __launch_bounds__(256) void k_gemm_qkv(
    const unsigned short* __restrict__ Ahg, const unsigned short* __restrict__ Bhg,
    const float* __restrict__ bias, unsigned short* __restrict__ Qs,
    unsigned short* __restrict__ Kks, unsigned short* __restrict__ VvT) {
  const int KD = 512;
  __shared__ __align__(16) unsigned short Ah_s[128 * 64];  // 16 KB
  __shared__ __align__(16) unsigned short Bh_s[96 * 64];   // 12 KB
  const int tid = threadIdx.x, lane = tid & 63, w = tid >> 6;
  // 64 blocks/XCD slab: m-range 512 rows (A 0.5MB) + full B (1.5MB) in L2
  const int bid = blockIdx.x;
  const int xcd = bid & 7, j5 = bid >> 3;             // j5: 0..63
  const int m0 = (xcd * 4 + (j5 >> 4)) * 128;         // 32 m-tiles
  const int n0 = (j5 & 15) * 96;                      // 16 n-tiles
  const int wm = (w >> 1) * 64, wn = (w & 1) * 48;

  f32x4 acc[4][3];
#pragma unroll
  for (int i = 0; i < 4; i++)
#pragma unroll
    for (int j = 0; j < 3; j++) acc[i][j] = (f32x4){0.f, 0.f, 0.f, 0.f};

  // chunk = 8 rows x 64 k x 2B = 1KB; lane l -> row l>>3, col (l&7)*8
  const int srw = lane >> 3, sc = (lane & 7) * 8;
  const int fm = lane & 15, fq = (lane >> 4) * 8;

  for (int k0 = 0; k0 < KD; k0 += 64) {
    __syncthreads();
#pragma unroll
    for (int ci = 0; ci < 7; ci++) {
      int c = w + ci * 4;                       // 0..27, wave-uniform
      if (c < 16) {                             // A chunks
        GLL16(Ahg + (size_t)(m0 + c * 8 + srw) * KD + k0 + sc, &Ah_s[c * 512]);
      } else {                                  // B chunks
        int cb = c - 16;
        GLL16(Bhg + (size_t)(n0 + cb * 8 + srw) * KD + k0 + sc, &Bh_s[cb * 512]);
      }
    }
    __builtin_amdgcn_s_waitcnt(0);
    __syncthreads();

#pragma unroll
    for (int kk = 0; kk < 2; kk++) {
      bf16x8 ah[4], bh[3];
#pragma unroll
      for (int i = 0; i < 4; i++)
        ah[i] = *(const bf16x8*)&Ah_s[(wm + i * 16 + fm) * 64 + kk * 32 + fq];
#pragma unroll
      for (int j = 0; j < 3; j++)
        bh[j] = *(const bf16x8*)&Bh_s[(wn + j * 16 + fm) * 64 + kk * 32 + fq];
#pragma unroll
      for (int i = 0; i < 4; i++)
#pragma unroll
        for (int j = 0; j < 3; j++)
          acc[i][j] = MFMA(ah[i], bh[j], acc[i][j]);
    }
  }

  // epilogue: C/D layout col=lane&15, row=quad*4+r  [m89-verified]
  const int quad = lane >> 4;
#pragma unroll
  for (int i = 0; i < 4; i++)
#pragma unroll
    for (int j = 0; j < 3; j++) {
      int gn = n0 + wn + j * 16 + fm;          // 16-aligned base: sec uniform
      float bv = bias[gn];
      int sec = gn >> 9, cc = gn & 511;
      int h = cc >> 6, d = cc & 63;
      int gm0 = m0 + wm + i * 16 + quad * 4;   // 4-aligned t base
      int bb = gm0 >> 11, t = gm0 & 2047;
      if (sec == 2) {  // V^T [B,H,64,2048]: 4 consecutive t -> one 8B store
        ushort4 pk;
        pk.x = f2bf(acc[i][j][0] + bv);
        pk.y = f2bf(acc[i][j][1] + bv);
        pk.z = f2bf(acc[i][j][2] + bv);
        pk.w = f2bf(acc[i][j][3] + bv);
        *(ushort4*)&VvT[(((size_t)(bb * 8 + h)) * 64 + d) * 2048 + t] = pk;
      } else {
        unsigned short* dst = sec == 0 ? Qs : Kks;
        float mul = sec == 0 ? 0.125f : 1.0f;  // 1/sqrt(64), exact
#pragma unroll
        for (int r = 0; r < 4; r++) {
          float v = (acc[i][j][r] + bv) * mul;
          dst[(((size_t)(bb * 8 + h)) * 2048 + t + r) * 64 + d] = f2bf(v);
        }
      }
    }
}

// ---------------------------------------------------------------------------
// Out-proj GEMM fused with final transpose * x + relu. Single-pass bf16.
// Tile 64m x 64n, BK=64, grid 512 (64m x 8n): 2+ blocks/CU co-resident.
// Epilogue: LDS transpose -> out[b,e,t] = relu(C[b,t,e] * x[b,e,t]).
__global__ __launch_bounds__(256) void k_gemm_out(
    const unsigned short* __restrict__ Ahg, const unsigned short* __restrict__ Bhg,
    const float* __restrict__ bias, const float* __restrict__ x,
    float* __restrict__ out) {
  const int KD = 512;
  __shared__ __align__(16) union {
    struct {
      unsigned short Ah[64 * 64];   // 8 KB
      unsigned short Bh[64 * 64];   // 8 KB
    } st;
    float tile[64][65];             // 16.6 KB epilogue transpose
  } u;
  const int tid = threadIdx.x, lane = tid & 63, w = tid >> 6;
  // 64 blocks/XCD slab: 8m x 8n (x/out slab ~2MB + A/B 1MB in L2)
  const int bid = blockIdx.x;
  const int xcd = bid & 7, j5 = bid >> 3;             // j5: 0..63
  const int m0 = (xcd * 8 + (j5 >> 3)) * 64;          // 64 m-tiles
  const int n0 = (j5 & 7) * 64;                       // 8 n-tiles
  const int wm = (w >> 1) * 32, wn = (w & 1) * 32;

  f32x4 acc[2][2];
#pragma unroll
  for (int i = 0; i < 2; i++)
#pragma unroll
    for (int j = 0; j < 2; j++) acc[i][j] = (f32x4){0.f, 0.f, 0.f, 0.f};

  const int srw = lane >> 3, sc = (lane & 7) * 8;
  const int fm = lane & 15, fq = (lane >> 4) * 8;

  for (int k0 = 0; k0 < KD; k0 += 64) {
    __syncthreads();
#pragma unroll
    for (int ci = 0; ci < 4; ci++) {
      int c = w + ci * 4;                       // 0..15, wave-uniform
      if (c < 8) {                              // A chunks (8 rows each)
        GLL16(Ahg + (size_t)(m0 + c * 8 + srw) * KD + k0 + sc, &u.st.Ah[c * 512]);
      } else {
        int cb = c - 8;
        GLL16(Bhg + (size_t)(n0 + cb * 8 + srw) * KD + k0 + sc, &u.st.Bh[cb * 512]);
      }
    }
    __builtin_amdgcn_s_waitcnt(0);
    __syncthreads();

#pragma unroll
    for (int kk = 0; kk < 2; kk++) {
      bf16x8 ah[2], bh[2];
#pragma unroll
      for (int i = 0; i < 2; i++)
        ah[i] = *(const bf16x8*)&u.st.Ah[(wm + i * 16 + fm) * 64 + kk * 32 + fq];
#pragma unroll
      for (int j = 0; j < 2; j++)
        bh[j] = *(const bf16x8*)&u.st.Bh[(wn + j * 16 + fm) * 64 + kk * 32 + fq];
#pragma unroll
      for (int i = 0; i < 2; i++)
#pragma unroll
        for (int j = 0; j < 2; j++)
          acc[i][j] = MFMA(ah[i], bh[j], acc[i][j]);
    }
  }

  __syncthreads();  // all frag reads done before tile overwrites staging
  // write acc+bias into transpose tile: tile[t_local][e_local]
  const int quad = lane >> 4;
#pragma unroll
  for (int i = 0; i < 2; i++)
#pragma unroll
    for (int j = 0; j < 2; j++) {
      int ln = wn + j * 16 + fm;
      float bv = bias[n0 + ln];
#pragma unroll
      for (int r = 0; r < 4; r++) {
        int lm = wm + i * 16 + quad * 4 + r;
        u.tile[lm][ln] = acc[i][j][r] + bv;
      }
    }
  __syncthreads();

  // out[b,e,t] = relu(tile[t][e] * x[b,e,t]); coalesced along t
  const int bb = m0 >> 11, t0 = m0 & 2047;
  const int tt = tid & 63, e0w = tid >> 6;
#pragma unroll
  for (int k = 0; k < 16; k++) {
    int ee = e0w + k * 4;
    size_t o = ((size_t)bb * 512 + n0 + ee) * 2048 + t0 + tt;
    float v = u.tile[tt][ee] * x[o];
    out[o] = fmaxf(v, 0.f);
  }
}

// ---------------------------------------------------------------------------
// K2: local attention, barrier-free (R9 structure, harness-verified).
#define PSTR 200  // P row stride (bf16)
__global__ __launch_bounds__(256, 4) void k_attention(
    const unsigned short* __restrict__ Qs, const unsigned short* __restrict__ Kks,
    const unsigned short* __restrict__ VvT, unsigned short* __restrict__ ctx_hi) {
  __shared__ __align__(16) unsigned short P_s[64 * PSTR];  // 25.6 KB

  const int tid = threadIdx.x, lane = tid & 63, w = tid >> 6;
  const int q0 = blockIdx.x * 64;
  const int bh = blockIdx.y;
  const int j0 = q0 - 64;                    // window base key
  const size_t base = (size_t)bh * 2048 * 64;
  const int fm = lane & 15, quad = lane >> 4;

  // Q A-fragments for this wave's 16 rows (pre-scaled by 1/8 in QKV epilogue)
  bf16x8 aq[2];
  {
    const size_t qb = base + (size_t)(q0 + w * 16 + fm) * 64 + quad * 8;
#pragma unroll
    for (int ks = 0; ks < 2; ks++)
      aq[ks] = *(const bf16x8*)&Qs[qb + ks * 32];
  }

  // S = Q @ K^T over 10 key tiles; covers this wave's valid window AND the
  // P columns PV reads, so skipped/masked tiles give P=0.
  const int ct0 = (w >> 1) * 2;
  f32x4 sa[10];
#pragma unroll
  for (int u2 = 0; u2 < 10; u2++) sa[u2] = (f32x4){0.f, 0.f, 0.f, 0.f};
  __builtin_amdgcn_s_setprio(1);
#pragma unroll
  for (int u2 = 0; u2 < 10; u2++) {
    int jr = j0 + (ct0 + u2) * 16 + fm;
    jr = jr < 0 ? 0 : (jr > 2047 ? 2047 : jr);     // clamp: finite, masked below
    const unsigned short* kp = &Kks[base + (size_t)jr * 64 + quad * 8];
#pragma unroll
    for (int ks = 0; ks < 2; ks++) {
      bf16x8 bk = *(const bf16x8*)&kp[ks * 32];
      sa[u2] = MFMA(aq[ks], bk, sa[u2]);
    }
  }
  __builtin_amdgcn_s_setprio(0);

  // mask (REPLACE) + per-row max
  float rm[4], rs[4], inv[4];
#pragma unroll
  for (int r = 0; r < 4; r++) rm[r] = -1e30f;
#pragma unroll
  for (int u2 = 0; u2 < 10; u2++) {
    int jj = (ct0 + u2) * 16 + fm;               // block-local key col
    int jg = j0 + jj;
    bool jok = (jg >= 0) && (jg < 2048);
#pragma unroll
    for (int r = 0; r < 4; r++) {
      int ii = w * 16 + quad * 4 + r;            // block-local query row
      bool ok = jok && (jj >= ii) && (jj <= ii + 128);
      float sv = ok ? sa[u2][r] : -1e30f;
      sa[u2][r] = sv;
      rm[r] = fmaxf(rm[r], sv);
    }
  }
#pragma unroll
  for (int off = 1; off < 16; off <<= 1)
#pragma unroll
    for (int r = 0; r < 4; r++) rm[r] = fmaxf(rm[r], __shfl_xor(rm[r], off));
#pragma unroll
  for (int r = 0; r < 4; r++) rs[r] = 0.f;
#pragma unroll
  for (int u2 = 0; u2 < 10; u2++)
#pragma unroll
    for (int r = 0; r < 4; r++) {
      float e = __expf(sa[u2][r] - rm[r]);
      sa[u2][r] = e;
      rs[r] += e;
    }
#pragma unroll
  for (int off = 1; off < 16; off <<= 1)
#pragma unroll
    for (int r = 0; r < 4; r++) rs[r] += __shfl_xor(rs[r], off);
#pragma unroll
  for (int r = 0; r < 4; r++) inv[r] = 1.0f / rs[r];

  // P (bf16) -> wave-private LDS slab; intra-wave: lgkmcnt(0) + sched fence.
#pragma unroll
  for (int u2 = 0; u2 < 10; u2++)
#pragma unroll
    for (int r = 0; r < 4; r++) {
      int row = w * 16 + quad * 4 + r;
      P_s[row * PSTR + (ct0 + u2) * 16 + fm] = f2bf(sa[u2][r] * inv[r]);
    }
  asm volatile("s_waitcnt lgkmcnt(0)" ::: "memory");
  __builtin_amdgcn_sched_barrier(0);

  // ctx = P @ V^T direct from global; 5 k-slots cover the wave's window.
  const int ks0 = w >> 1;
  f32x4 oa[4];
#pragma unroll
  for (int dt = 0; dt < 4; dt++) oa[dt] = (f32x4){0.f, 0.f, 0.f, 0.f};
  __builtin_amdgcn_s_setprio(1);
#pragma unroll
  for (int ku = 0; ku < 5; ku++) {
    int ks = ks0 + ku;
    bf16x8 ap = *(const bf16x8*)&P_s[(w * 16 + fm) * PSTR + ks * 32 + quad * 8];
    int j = j0 + ks * 32 + quad * 8;             // 8-aligned chunk
    j = (j < 0 || j > 2040) ? 0 : j;             // OOB chunk -> valid addr (P=0)
    const unsigned short* vp = &VvT[base + j];
#pragma unroll
    for (int dt = 0; dt < 4; dt++) {
      bf16x8 bv = *(const bf16x8*)&vp[(size_t)(dt * 16 + fm) * 2048];
      oa[dt] = MFMA(ap, bv, oa[dt]);
    }
  }
  __builtin_amdgcn_s_setprio(0);

  // write ctx bf16 [B*T, 512]
  const int bb = bh >> 3, h = bh & 7;
#pragma unroll
  for (int dt = 0; dt < 4; dt++)
#pragma unroll
    for (int r = 0; r < 4; r++) {
      int t = q0 + w * 16 + quad * 4 + r;
      int c = h * 64 + dt * 16 + fm;
      ctx_hi[((size_t)(bb * 2048 + t)) * 512 + c] = f2bf(oa[dt][r]);
    }
}

// ---------------------------------------------------------------------------
extern "C" void kernel_launch(void* const* d_in, const int* in_sizes, int n_in,
                              void* d_out, int out_size, void* d_ws, size_t ws_size,
                              hipStream_t stream) {
  const float* x = (const float*)d_in[0];
  const float* w_in = (const float*)d_in[1];
  const float* b_in = (const float*)d_in[2];
  const float* w_out = (const float*)d_in[3];
  const float* b_out = (const float*)d_in[4];
  float* out = (float*)d_out;

  uint8_t* ws = (uint8_t*)d_ws;
  unsigned short* xT_hi = (unsigned short*)(ws + 0);           // 4 MiB
  unsigned short* wih   = (unsigned short*)(ws + 8388608);     // 1.5 MiB
  unsigned short* woh   = (unsigned short*)(ws + 9961472);     // 0.5 MiB
  unsigned short* Qs    = (unsigned short*)(ws + 12582912);    // 4 MiB
  unsigned short* Kk    = (unsigned short*)(ws + 16777216);    // 4 MiB
  unsigned short* VvT   = (unsigned short*)(ws + 20971520);    // 4 MiB [B,H,64,T]
  unsigned short* ctxh  = (unsigned short*)(ws + 25165824);    // 4 MiB

  k_prep<<<dim3(32, 9, 2), 256, 0, stream>>>(x, w_in, w_out, xT_hi, wih, woh);
  k_gemm_qkv<<<512, 256, 0, stream>>>(xT_hi, wih, b_in, Qs, Kk, VvT);
  k_attention<<<dim3(32, 16), 256, 0, stream>>>(Qs, Kk, VvT, ctxh);
  k_gemm_out<<<512, 256, 0, stream>>>(ctxh, woh, b_out, x, out);
}

// Round 6
// 115.255 us; speedup vs baseline: 1.0452x; 1.0452x over previous
//
#include <hip/hip_runtime.h>
#include <stdint.h>

// Encoder: B=2,E=512,T=2048,H=8,dh=64, local window |i-j|<=64
// R14: identical to R13 (unmeasured — GPU acquisition timeout). Re-audit of
//     the one changed kernel (k_prep) found no defects; resubmitting so the
//     next successful bench measures exactly R13's delta.
// R13: REVERT R11/R12 GEMM re-tiling — measured regression (115.16->120.46).
//     GEMMs are staging-bound; R11 increased staged bytes (qkv 96->112MB,
//     out 48->64MB). Prior session bracketed 128x128/384 + 64x128/256 as
//     optimum; restored verbatim.
//     Kept from R11: k_prep vectorization only (float4/ushort4, 64x64 tile).
//     k_attention: R9 barrier-free structure (harness-verified, 115.16).

#define DEVI __device__ __forceinline__

typedef __attribute__((ext_vector_type(8))) short bf16x8;   // 8 bf16 in 4 VGPRs
typedef __attribute__((ext_vector_type(4))) float f32x4;

DEVI unsigned short f2bf(float f) {               // RNE float->bf16
  unsigned u = __float_as_uint(f);
  u += 0x7fffu + ((u >> 16) & 1u);
  return (unsigned short)(u >> 16);
}
DEVI float bf2f(unsigned short h) { return __uint_as_float(((unsigned)h) << 16); }

#define GLL16(gp, lp)                                                          \
  __builtin_amdgcn_global_load_lds(                                            \
      (const __attribute__((address_space(1))) void*)(gp),                     \
      (__attribute__((address_space(3))) void*)(lp), 16, 0, 0)

#define MFMA(a, b, c) __builtin_amdgcn_mfma_f32_16x16x32_bf16((a), (b), (c), 0, 0, 0)

// ---------------------------------------------------------------------------
// K0: blockIdx.y<8: x[B,E,T] fp32 -> xT[B*T,512] bf16 (64x64 transpose tiles)
//     blockIdx.y==8: w_in/w_out fp32 -> bf16 (64 rider blocks x 16384 elems)
__global__ __launch_bounds__(256) void k_prep(
    const float* __restrict__ x, const float* __restrict__ w_in,
    const float* __restrict__ w_out, unsigned short* __restrict__ xh,
    unsigned short* __restrict__ wih, unsigned short* __restrict__ woh) {
  const int tid = threadIdx.x;
  if (blockIdx.y == 8) {  // weight convert rider
    int cb = (blockIdx.z << 5) | blockIdx.x;   // 0..63
    const float* src;
    unsigned short* dst;
    int base;
    if (cb < 48) {        // 48*16384 = 786432 = w_in exactly
      src = w_in; dst = wih; base = cb * 16384;
    } else {              // 16*16384 = 262144 = w_out exactly
      src = w_out; dst = woh; base = (cb - 48) * 16384;
    }
#pragma unroll
    for (int k = 0; k < 16; k++) {
      int idx = base + (k * 256 + tid) * 4;
      float4 v = *(const float4*)&src[idx];
      ushort4 o;
      o.x = f2bf(v.x); o.y = f2bf(v.y); o.z = f2bf(v.z); o.w = f2bf(v.w);
      *(ushort4*)&dst[idx] = o;
    }
    return;
  }
  __shared__ float tile[64][65];   // 16.6 KB
  const int b = blockIdx.z, e0 = blockIdx.y * 64, t0 = blockIdx.x * 64;
  const int g = tid >> 4, c4 = (tid & 15) * 4;   // g: 0..15
#pragma unroll
  for (int p = 0; p < 4; p++) {
    int el = p * 16 + g;
    float4 v = *(const float4*)&x[((size_t)b * 512 + e0 + el) * 2048 + t0 + c4];
    tile[el][c4 + 0] = v.x; tile[el][c4 + 1] = v.y;
    tile[el][c4 + 2] = v.z; tile[el][c4 + 3] = v.w;
  }
  __syncthreads();
#pragma unroll
  for (int p = 0; p < 4; p++) {
    int tl = p * 16 + g;
    ushort4 o;
    o.x = f2bf(tile[c4 + 0][tl]);
    o.y = f2bf(tile[c4 + 1][tl]);
    o.z = f2bf(tile[c4 + 2][tl]);
    o.w = f2bf(tile[c4 + 3][tl]);
    *(ushort4*)&xh[((size_t)(b * 2048 + t0 + tl)) * 512 + e0 + c4] = o;
  }
}

// ---------------------------------------------------------------------------
// QKV GEMM: C[m,n] = sum_k Ah[m,k]*Bh[n,k] + bias[n], 128x128 tile, BK=32.
// Grid: 384 linear, XCD-swizzled. Epilogue: Q(*0.125)/K -> [B,H,T,64] bf16,
// V -> TRANSPOSED [B,H,64,T] bf16 (packed ushort4, 4 consecutive t/thread).
// (Measured-best config; bracketed optimum from prior session.)
__global__ __launch_bounds__(256) void k_gemm_qkv(
    const unsigned short* __restrict__ Ahg, const unsigned short* __restrict__ Bhg,
    const float* __restrict__ bias, unsigned short* __restrict__ Qs,
    unsigned short* __restrict__ Kks, unsigned short* __restrict__ VvT) {
  const int KD = 512;
  __shared__ __align__(16) unsigned short Ah_s[128 * 32];
  __shared__ __align__(16) unsigned short Bh_s[128 * 32];
  const int tid = threadIdx.x, lane = tid & 63, w = tid >> 6;
  // XCD swizzle: dispatch heuristic xcd = bid%8; 48 blocks/XCD = 4m x 12n slab
  const int bid = blockIdx.x;
  const int xcd = bid & 7, j5 = bid >> 3;
  const int m0 = (xcd * 4 + j5 / 12) * 128, n0 = (j5 % 12) * 128;
  const int wm = (w >> 1) * 64, wn = (w & 1) * 64;

  f32x4 acc[4][4];
#pragma unroll
  for (int i = 0; i < 4; i++)
#pragma unroll
    for (int j = 0; j < 4; j++) acc[i][j] = (f32x4){0.f, 0.f, 0.f, 0.f};

  const int srw = lane >> 2, sc = (lane & 3) * 8;
  const size_t b0 = (size_t)(n0 + w * 32 + srw) * KD + sc;
  const size_t b1 = b0 + (size_t)16 * KD;
  unsigned short* lB0 = &Bh_s[(w * 32) * 32];
  unsigned short* lB1 = &Bh_s[(w * 32 + 16) * 32];
  const size_t a0 = (size_t)(m0 + w * 32 + srw) * KD + sc;
  const size_t a1 = a0 + (size_t)16 * KD;
  unsigned short* lAh0 = &Ah_s[(w * 32) * 32];
  unsigned short* lAh1 = &Ah_s[(w * 32 + 16) * 32];

  const int fm = lane & 15, fq = (lane >> 4) * 8;

  for (int k0 = 0; k0 < KD; k0 += 32) {
    __syncthreads();
    GLL16(Ahg + a0 + k0, lAh0);
    GLL16(Ahg + a1 + k0, lAh1);
    GLL16(Bhg + b0 + k0, lB0);
    GLL16(Bhg + b1 + k0, lB1);
    __builtin_amdgcn_s_waitcnt(0);
    __syncthreads();

    bf16x8 ah[4], bh[4];
#pragma unroll
    for (int i = 0; i < 4; i++) {
      ah[i] = *(const bf16x8*)&Ah_s[(wm + i * 16 + fm) * 32 + fq];
      bh[i] = *(const bf16x8*)&Bh_s[(wn + i * 16 + fm) * 32 + fq];
    }
#pragma unroll
    for (int i = 0; i < 4; i++)
#pragma unroll
      for (int j = 0; j < 4; j++)
        acc[i][j] = MFMA(ah[i], bh[j], acc[i][j]);
  }

  // epilogue: C/D layout col=lane&15, row=quad*4+r  [m89-verified]
  const int quad = lane >> 4;
#pragma unroll
  for (int i = 0; i < 4; i++)
#pragma unroll
    for (int j = 0; j < 4; j++) {
      int gn = n0 + wn + j * 16 + fm;
      float bv = bias[gn];
      int sec = gn >> 9, cc = gn & 511;
      int h = cc >> 6, d = cc & 63;
      int gm0 = m0 + wm + i * 16 + quad * 4;       // 4-aligned t base
      int bb = gm0 >> 11, t = gm0 & 2047;
      if (sec == 2) {  // V^T [B,H,64,2048]: 4 consecutive t -> one 8B store
        ushort4 pk;
        pk.x = f2bf(acc[i][j][0] + bv);
        pk.y = f2bf(acc[i][j][1] + bv);
        pk.z = f2bf(acc[i][j][2] + bv);
        pk.w = f2bf(acc[i][j][3] + bv);
        *(ushort4*)&VvT[(((size_t)(bb * 8 + h)) * 64 + d) * 2048 + t] = pk;
      } else {
        unsigned short* dst = sec == 0 ? Qs : Kks;
        float mul = sec == 0 ? 0.125f : 1.0f;  // 1/sqrt(64), exact
#pragma unroll
        for (int r = 0; r < 4; r++) {
          float v = (acc[i][j][r] + bv) * mul;
          dst[(((size_t)(bb * 8 + h)) * 2048 + t + r) * 64 + d] = f2bf(v);
        }
      }
    }
}

// ---------------------------------------------------------------------------
// Out-proj GEMM fused with final transpose * x + relu. Single-pass bf16.
// C[m,n] = sum_k Ah[m,k]*Bh[n,k] + bias[n]; tile 64m x 128n, grid 256.
// Epilogue: LDS transpose -> out[b,e,t] = relu(C[b,t,e] * x[b,e,t]).
// (Measured-best config; bracketed optimum from prior session.)
__global__ __launch_bounds__(256) void k_gemm_out(
    const unsigned short* __restrict__ Ahg, const unsigned short* __restrict__ Bhg,
    const float* __restrict__ bias, const float* __restrict__ x,
    float* __restrict__ out) {
  const int KD = 512;
  __shared__ __align__(16) union {
    struct {
      unsigned short Ah[64 * 32];
      unsigned short Bh[128 * 32];
    } st;                       // 12 KB staging
    float tile[64][129];        // 32.25 KB epilogue transpose
  } u;
  const int tid = threadIdx.x, lane = tid & 63, w = tid >> 6;
  // XCD swizzle: 32 blocks/XCD = 8m x 4n slab (A 0.5 MB + B 0.5 MB in L2)
  const int bid = blockIdx.x;
  const int xcd = bid & 7, j5 = bid >> 3;
  const int m0 = (xcd * 8 + (j5 >> 2)) * 64, n0 = (j5 & 3) * 128;
  const int wm = (w >> 1) * 32, wn = (w & 1) * 64;

  f32x4 acc[2][4];
#pragma unroll
  for (int i = 0; i < 2; i++)
#pragma unroll
    for (int j = 0; j < 4; j++) acc[i][j] = (f32x4){0.f, 0.f, 0.f, 0.f};

  const int srw = lane >> 2, sc = (lane & 3) * 8;
  const size_t b0 = (size_t)(n0 + w * 32 + srw) * KD + sc;
  const size_t b1 = b0 + (size_t)16 * KD;
  const size_t a0 = (size_t)(m0 + w * 16 + srw) * KD + sc;
  unsigned short* lB0 = &u.st.Bh[(w * 32) * 32];
  unsigned short* lB1 = &u.st.Bh[(w * 32 + 16) * 32];
  unsigned short* lAh0 = &u.st.Ah[(w * 16) * 32];

  const int fm = lane & 15, fq = (lane >> 4) * 8;

  for (int k0 = 0; k0 < KD; k0 += 32) {
    __syncthreads();
    GLL16(Ahg + a0 + k0, lAh0);
    GLL16(Bhg + b0 + k0, lB0);
    GLL16(Bhg + b1 + k0, lB1);
    __builtin_amdgcn_s_waitcnt(0);
    __syncthreads();

    bf16x8 ah[2], bh[4];
#pragma unroll
    for (int i = 0; i < 2; i++)
      ah[i] = *(const bf16x8*)&u.st.Ah[(wm + i * 16 + fm) * 32 + fq];
#pragma unroll
    for (int j = 0; j < 4; j++)
      bh[j] = *(const bf16x8*)&u.st.Bh[(wn + j * 16 + fm) * 32 + fq];
#pragma unroll
    for (int i = 0; i < 2; i++)
#pragma unroll
      for (int j = 0; j < 4; j++)
        acc[i][j] = MFMA(ah[i], bh[j], acc[i][j]);
  }

  __syncthreads();  // all frag reads done before tile overwrites staging
  // write acc+bias into transpose tile: tile[t_local][e_local]
  const int quad = lane >> 4;
#pragma unroll
  for (int i = 0; i < 2; i++)
#pragma unroll
    for (int j = 0; j < 4; j++) {
      int ln = wn + j * 16 + fm;
      float bv = bias[n0 + ln];
#pragma unroll
      for (int r = 0; r < 4; r++) {
        int lm = wm + i * 16 + quad * 4 + r;
        u.tile[lm][ln] = acc[i][j][r] + bv;
      }
    }
  __syncthreads();

  // out[b,e,t] = relu(tile[t][e] * x[b,e,t]); coalesced along t
  const int bb = m0 >> 11, t0 = m0 & 2047;
  const int tt = tid & 63, e0w = tid >> 6;
#pragma unroll
  for (int k = 0; k < 32; k++) {
    int ee = e0w + k * 4;
    size_t o = ((size_t)bb * 512 + n0 + ee) * 2048 + t0 + tt;
    float v = u.tile[tt][ee] * x[o];
    out[o] = fmaxf(v, 0.f);
  }
}

// ---------------------------------------------------------------------------
// K2: local attention, barrier-free (R9 structure, harness-verified).
#define PSTR 200  // P row stride (bf16)
__global__ __launch_bounds__(256, 4) void k_attention(
    const unsigned short* __restrict__ Qs, const unsigned short* __restrict__ Kks,
    const unsigned short* __restrict__ VvT, unsigned short* __restrict__ ctx_hi) {
  __shared__ __align__(16) unsigned short P_s[64 * PSTR];  // 25.6 KB

  const int tid = threadIdx.x, lane = tid & 63, w = tid >> 6;
  const int q0 = blockIdx.x * 64;
  const int bh = blockIdx.y;
  const int j0 = q0 - 64;                    // window base key
  const size_t base = (size_t)bh * 2048 * 64;
  const int fm = lane & 15, quad = lane >> 4;

  // Q A-fragments for this wave's 16 rows (pre-scaled by 1/8 in QKV epilogue)
  bf16x8 aq[2];
  {
    const size_t qb = base + (size_t)(q0 + w * 16 + fm) * 64 + quad * 8;
#pragma unroll
    for (int ks = 0; ks < 2; ks++)
      aq[ks] = *(const bf16x8*)&Qs[qb + ks * 32];
  }

  // S = Q @ K^T over 10 key tiles; covers this wave's valid window AND the
  // P columns PV reads, so skipped/masked tiles give P=0.
  const int ct0 = (w >> 1) * 2;
  f32x4 sa[10];
#pragma unroll
  for (int u2 = 0; u2 < 10; u2++) sa[u2] = (f32x4){0.f, 0.f, 0.f, 0.f};
  __builtin_amdgcn_s_setprio(1);
#pragma unroll
  for (int u2 = 0; u2 < 10; u2++) {
    int jr = j0 + (ct0 + u2) * 16 + fm;
    jr = jr < 0 ? 0 : (jr > 2047 ? 2047 : jr);     // clamp: finite, masked below
    const unsigned short* kp = &Kks[base + (size_t)jr * 64 + quad * 8];
#pragma unroll
    for (int ks = 0; ks < 2; ks++) {
      bf16x8 bk = *(const bf16x8*)&kp[ks * 32];
      sa[u2] = MFMA(aq[ks], bk, sa[u2]);
    }
  }
  __builtin_amdgcn_s_setprio(0);

  // mask (REPLACE) + per-row max
  float rm[4], rs[4], inv[4];
#pragma unroll
  for (int r = 0; r < 4; r++) rm[r] = -1e30f;
#pragma unroll
  for (int u2 = 0; u2 < 10; u2++) {
    int jj = (ct0 + u2) * 16 + fm;               // block-local key col
    int jg = j0 + jj;
    bool jok = (jg >= 0) && (jg < 2048);
#pragma unroll
    for (int r = 0; r < 4; r++) {
      int ii = w * 16 + quad * 4 + r;            // block-local query row
      bool ok = jok && (jj >= ii) && (jj <= ii + 128);
      float sv = ok ? sa[u2][r] : -1e30f;
      sa[u2][r] = sv;
      rm[r] = fmaxf(rm[r], sv);
    }
  }
#pragma unroll
  for (int off = 1; off < 16; off <<= 1)
#pragma unroll
    for (int r = 0; r < 4; r++) rm[r] = fmaxf(rm[r], __shfl_xor(rm[r], off));
#pragma unroll
  for (int r = 0; r < 4; r++) rs[r] = 0.f;
#pragma unroll
  for (int u2 = 0; u2 < 10; u2++)
#pragma unroll
    for (int r = 0; r < 4; r++) {
      float e = __expf(sa[u2][r] - rm[r]);
      sa[u2][r] = e;
      rs[r] += e;
    }
#pragma unroll
  for (int off = 1; off < 16; off <<= 1)
#pragma unroll
    for (int r = 0; r < 4; r++) rs[r] += __shfl_xor(rs[r], off);
#pragma unroll
  for (int r = 0; r < 4; r++) inv[r] = 1.0f / rs[r];

  // P (bf16) -> wave-private LDS slab; intra-wave: lgkmcnt(0) + sched fence.
#pragma unroll
  for (int u2 = 0; u2 < 10; u2++)
#pragma unroll
    for (int r = 0; r < 4; r++) {
      int row = w * 16 + quad * 4 + r;
      P_s[row * PSTR + (ct0 + u2) * 16 + fm] = f2bf(sa[u2][r] * inv[r]);
    }
  asm volatile("s_waitcnt lgkmcnt(0)" ::: "memory");
  __builtin_amdgcn_sched_barrier(0);

  // ctx = P @ V^T direct from global; 5 k-slots cover the wave's window.
  const int ks0 = w >> 1;
  f32x4 oa[4];
#pragma unroll
  for (int dt = 0; dt < 4; dt++) oa[dt] = (f32x4){0.f, 0.f, 0.f, 0.f};
  __builtin_amdgcn_s_setprio(1);
#pragma unroll
  for (int ku = 0; ku < 5; ku++) {
    int ks = ks0 + ku;
    bf16x8 ap = *(const bf16x8*)&P_s[(w * 16 + fm) * PSTR + ks * 32 + quad * 8];
    int j = j0 + ks * 32 + quad * 8;             // 8-aligned chunk
    j = (j < 0 || j > 2040) ? 0 : j;             // OOB chunk -> valid addr (P=0)
    const unsigned short* vp = &VvT[base + j];
#pragma unroll
    for (int dt = 0; dt < 4; dt++) {
      bf16x8 bv = *(const bf16x8*)&vp[(size_t)(dt * 16 + fm) * 2048];
      oa[dt] = MFMA(ap, bv, oa[dt]);
    }
  }
  __builtin_amdgcn_s_setprio(0);

  // write ctx bf16 [B*T, 512]
  const int bb = bh >> 3, h = bh & 7;
#pragma unroll
  for (int dt = 0; dt < 4; dt++)
#pragma unroll
    for (int r = 0; r < 4; r++) {
      int t = q0 + w * 16 + quad * 4 + r;
      int c = h * 64 + dt * 16 + fm;
      ctx_hi[((size_t)(bb * 2048 + t)) * 512 + c] = f2bf(oa[dt][r]);
    }
}

// ---------------------------------------------------------------------------
extern "C" void kernel_launch(void* const* d_in, const int* in_sizes, int n_in,
                              void* d_out, int out_size, void* d_ws, size_t ws_size,
                              hipStream_t stream) {
  const float* x = (const float*)d_in[0];
  const float* w_in = (const float*)d_in[1];
  const float* b_in = (const float*)d_in[2];
  const float* w_out = (const float*)d_in[3];
  const float* b_out = (const float*)d_in[4];
  float* out = (float*)d_out;

  uint8_t* ws = (uint8_t*)d_ws;
  unsigned short* xT_hi = (unsigned short*)(ws + 0);           // 4 MiB
  unsigned short* wih   = (unsigned short*)(ws + 8388608);     // 1.5 MiB
  unsigned short* woh   = (unsigned short*)(ws + 9961472);     // 0.5 MiB
  unsigned short* Qs    = (unsigned short*)(ws + 12582912);    // 4 MiB
  unsigned short* Kk    = (unsigned short*)(ws + 16777216);    // 4 MiB
  unsigned short* VvT   = (unsigned short*)(ws + 20971520);    // 4 MiB [B,H,64,T]
  unsigned short* ctxh  = (unsigned short*)(ws + 25165824);    // 4 MiB

  k_prep<<<dim3(32, 9, 2), 256, 0, stream>>>(x, w_in, w_out, xT_hi, wih, woh);
  k_gemm_qkv<<<384, 256, 0, stream>>>(xT_hi, wih, b_in, Qs, Kk, VvT);
  k_attention<<<dim3(32, 16), 256, 0, stream>>>(Qs, Kk, VvT, ctxh);
  k_gemm_out<<<256, 256, 0, stream>>>(ctxh, woh, b_out, x, out);
}

// Round 7
// 114.168 us; speedup vs baseline: 1.0551x; 1.0095x over previous
//
#include <hip/hip_runtime.h>
#include <stdint.h>

// Encoder: B=2,E=512,T=2048,H=8,dh=64, local window |i-j|<=64
// R15: double-buffered stage-ahead K-loop in BOTH GEMMs (catalog T3 minimum
//     recipe, m248-verified): stage(k+1,buf^1) -> compute(buf) -> barrier.
//     Next tile's global_load_lds overlap current MFMA; 1 barrier/step
//     (was 2) and the serial stage->vmcnt(0) drain leaves the critical
//     path. Static buffer alternation (unroll-by-2, named buffers).
//     LDS: qkv 16->32 KB (2 blocks/CU unchanged), out 33 KB (unchanged).
//     Tile/grid configs stay at measured-best (128x128/384, 64x128/256).
//     k_prep (vectorized, measured-null) and k_attention (R9) untouched.
// R14: measured 115.26us (==R10 115.16 within noise): revert confirmed,
//     prep vectorization null. Window = ~86us harness fills + ~30us kernels.

#define DEVI __device__ __forceinline__

typedef __attribute__((ext_vector_type(8))) short bf16x8;   // 8 bf16 in 4 VGPRs
typedef __attribute__((ext_vector_type(4))) float f32x4;

DEVI unsigned short f2bf(float f) {               // RNE float->bf16
  unsigned u = __float_as_uint(f);
  u += 0x7fffu + ((u >> 16) & 1u);
  return (unsigned short)(u >> 16);
}
DEVI float bf2f(unsigned short h) { return __uint_as_float(((unsigned)h) << 16); }

#define GLL16(gp, lp)                                                          \
  __builtin_amdgcn_global_load_lds(                                            \
      (const __attribute__((address_space(1))) void*)(gp),                     \
      (__attribute__((address_space(3))) void*)(lp), 16, 0, 0)

#define MFMA(a, b, c) __builtin_amdgcn_mfma_f32_16x16x32_bf16((a), (b), (c), 0, 0, 0)

// ---------------------------------------------------------------------------
// K0: blockIdx.y<8: x[B,E,T] fp32 -> xT[B*T,512] bf16 (64x64 transpose tiles)
//     blockIdx.y==8: w_in/w_out fp32 -> bf16 (64 rider blocks x 16384 elems)
__global__ __launch_bounds__(256) void k_prep(
    const float* __restrict__ x, const float* __restrict__ w_in,
    const float* __restrict__ w_out, unsigned short* __restrict__ xh,
    unsigned short* __restrict__ wih, unsigned short* __restrict__ woh) {
  const int tid = threadIdx.x;
  if (blockIdx.y == 8) {  // weight convert rider
    int cb = (blockIdx.z << 5) | blockIdx.x;   // 0..63
    const float* src;
    unsigned short* dst;
    int base;
    if (cb < 48) {        // 48*16384 = 786432 = w_in exactly
      src = w_in; dst = wih; base = cb * 16384;
    } else {              // 16*16384 = 262144 = w_out exactly
      src = w_out; dst = woh; base = (cb - 48) * 16384;
    }
#pragma unroll
    for (int k = 0; k < 16; k++) {
      int idx = base + (k * 256 + tid) * 4;
      float4 v = *(const float4*)&src[idx];
      ushort4 o;
      o.x = f2bf(v.x); o.y = f2bf(v.y); o.z = f2bf(v.z); o.w = f2bf(v.w);
      *(ushort4*)&dst[idx] = o;
    }
    return;
  }
  __shared__ float tile[64][65];   // 16.6 KB
  const int b = blockIdx.z, e0 = blockIdx.y * 64, t0 = blockIdx.x * 64;
  const int g = tid >> 4, c4 = (tid & 15) * 4;   // g: 0..15
#pragma unroll
  for (int p = 0; p < 4; p++) {
    int el = p * 16 + g;
    float4 v = *(const float4*)&x[((size_t)b * 512 + e0 + el) * 2048 + t0 + c4];
    tile[el][c4 + 0] = v.x; tile[el][c4 + 1] = v.y;
    tile[el][c4 + 2] = v.z; tile[el][c4 + 3] = v.w;
  }
  __syncthreads();
#pragma unroll
  for (int p = 0; p < 4; p++) {
    int tl = p * 16 + g;
    ushort4 o;
    o.x = f2bf(tile[c4 + 0][tl]);
    o.y = f2bf(tile[c4 + 1][tl]);
    o.z = f2bf(tile[c4 + 2][tl]);
    o.w = f2bf(tile[c4 + 3][tl]);
    *(ushort4*)&xh[((size_t)(b * 2048 + t0 + tl)) * 512 + e0 + c4] = o;
  }
}

// ---------------------------------------------------------------------------
// QKV GEMM: C[m,n] = sum_k Ah[m,k]*Bh[n,k] + bias[n], 128x128 tile, BK=32,
// grid 384 XCD-swizzled, DOUBLE-BUFFERED stage-ahead K-loop.
// Epilogue: Q(*0.125)/K -> [B,H,T,64] bf16, V -> [B,H,64,T] bf16 (ushort4).
__global__ __launch_bounds__(256) void k_gemm_qkv(
    const unsigned short* __restrict__ Ahg, const unsigned short* __restrict__ Bhg,
    const float* __restrict__ bias, unsigned short* __restrict__ Qs,
    unsigned short* __restrict__ Kks, unsigned short* __restrict__ VvT) {
  const int KD = 512;
  __shared__ __align__(16) unsigned short Ah_s[2 * 128 * 32];  // 16 KB
  __shared__ __align__(16) unsigned short Bh_s[2 * 128 * 32];  // 16 KB
  const int tid = threadIdx.x, lane = tid & 63, w = tid >> 6;
  // XCD swizzle: dispatch heuristic xcd = bid%8; 48 blocks/XCD = 4m x 12n slab
  const int bid = blockIdx.x;
  const int xcd = bid & 7, j5 = bid >> 3;
  const int m0 = (xcd * 4 + j5 / 12) * 128, n0 = (j5 % 12) * 128;
  const int wm = (w >> 1) * 64, wn = (w & 1) * 64;

  f32x4 acc[4][4];
#pragma unroll
  for (int i = 0; i < 4; i++)
#pragma unroll
    for (int j = 0; j < 4; j++) acc[i][j] = (f32x4){0.f, 0.f, 0.f, 0.f};

  const int srw = lane >> 2, sc = (lane & 3) * 8;
  const size_t b0 = (size_t)(n0 + w * 32 + srw) * KD + sc;
  const size_t b1 = b0 + (size_t)16 * KD;
  const size_t a0 = (size_t)(m0 + w * 32 + srw) * KD + sc;
  const size_t a1 = a0 + (size_t)16 * KD;

  unsigned short* A0 = Ah_s;
  unsigned short* A1 = Ah_s + 128 * 32;
  unsigned short* B0 = Bh_s;
  unsigned short* B1 = Bh_s + 128 * 32;

  const int fm = lane & 15, fq = (lane >> 4) * 8;
  const int lA0 = (w * 32) * 32, lA1 = (w * 32 + 16) * 32;

  auto stage = [&](int kk, unsigned short* A, unsigned short* B) {
    GLL16(Ahg + a0 + kk, A + lA0);
    GLL16(Ahg + a1 + kk, A + lA1);
    GLL16(Bhg + b0 + kk, B + lA0);
    GLL16(Bhg + b1 + kk, B + lA1);
  };
  auto compute = [&](const unsigned short* A, const unsigned short* B) {
    bf16x8 ah[4], bh[4];
#pragma unroll
    for (int i = 0; i < 4; i++) {
      ah[i] = *(const bf16x8*)&A[(wm + i * 16 + fm) * 32 + fq];
      bh[i] = *(const bf16x8*)&B[(wn + i * 16 + fm) * 32 + fq];
    }
#pragma unroll
    for (int i = 0; i < 4; i++)
#pragma unroll
      for (int j = 0; j < 4; j++)
        acc[i][j] = MFMA(ah[i], bh[j], acc[i][j]);
  };

  stage(0, A0, B0);
  __syncthreads();                       // auto vmcnt(0) drain
#pragma unroll
  for (int k0 = 0; k0 < KD; k0 += 64) {
    if (k0 + 32 < KD) stage(k0 + 32, A1, B1);  // fly during compute(A0)
    compute(A0, B0);
    __syncthreads();
    if (k0 + 64 < KD) stage(k0 + 64, A0, B0);  // fly during compute(A1)
    compute(A1, B1);
    __syncthreads();
  }

  // epilogue: C/D layout col=lane&15, row=quad*4+r  [m89-verified]
  const int quad = lane >> 4;
#pragma unroll
  for (int i = 0; i < 4; i++)
#pragma unroll
    for (int j = 0; j < 4; j++) {
      int gn = n0 + wn + j * 16 + fm;
      float bv = bias[gn];
      int sec = gn >> 9, cc = gn & 511;
      int h = cc >> 6, d = cc & 63;
      int gm0 = m0 + wm + i * 16 + quad * 4;       // 4-aligned t base
      int bb = gm0 >> 11, t = gm0 & 2047;
      if (sec == 2) {  // V^T [B,H,64,2048]: 4 consecutive t -> one 8B store
        ushort4 pk;
        pk.x = f2bf(acc[i][j][0] + bv);
        pk.y = f2bf(acc[i][j][1] + bv);
        pk.z = f2bf(acc[i][j][2] + bv);
        pk.w = f2bf(acc[i][j][3] + bv);
        *(ushort4*)&VvT[(((size_t)(bb * 8 + h)) * 64 + d) * 2048 + t] = pk;
      } else {
        unsigned short* dst = sec == 0 ? Qs : Kks;
        float mul = sec == 0 ? 0.125f : 1.0f;  // 1/sqrt(64), exact
#pragma unroll
        for (int r = 0; r < 4; r++) {
          float v = (acc[i][j][r] + bv) * mul;
          dst[(((size_t)(bb * 8 + h)) * 2048 + t + r) * 64 + d] = f2bf(v);
        }
      }
    }
}

// ---------------------------------------------------------------------------
// Out-proj GEMM fused with final transpose * x + relu. Single-pass bf16.
// Tile 64m x 128n, grid 256, DOUBLE-BUFFERED stage-ahead K-loop.
// Epilogue: LDS transpose -> out[b,e,t] = relu(C[b,t,e] * x[b,e,t]).
__global__ __launch_bounds__(256) void k_gemm_out(
    const unsigned short* __restrict__ Ahg, const unsigned short* __restrict__ Bhg,
    const float* __restrict__ bias, const float* __restrict__ x,
    float* __restrict__ out) {
  const int KD = 512;
  __shared__ __align__(16) union {
    struct {
      unsigned short Ah[2 * 64 * 32];    // 8 KB
      unsigned short Bh[2 * 128 * 32];   // 16 KB
    } st;                       // 24 KB staging
    float tile[64][129];        // 32.25 KB epilogue transpose
  } u;
  const int tid = threadIdx.x, lane = tid & 63, w = tid >> 6;
  // XCD swizzle: 32 blocks/XCD = 8m x 4n slab (A 0.5 MB + B 0.5 MB in L2)
  const int bid = blockIdx.x;
  const int xcd = bid & 7, j5 = bid >> 3;
  const int m0 = (xcd * 8 + (j5 >> 2)) * 64, n0 = (j5 & 3) * 128;
  const int wm = (w >> 1) * 32, wn = (w & 1) * 64;

  f32x4 acc[2][4];
#pragma unroll
  for (int i = 0; i < 2; i++)
#pragma unroll
    for (int j = 0; j < 4; j++) acc[i][j] = (f32x4){0.f, 0.f, 0.f, 0.f};

  const int srw = lane >> 2, sc = (lane & 3) * 8;
  const size_t b0 = (size_t)(n0 + w * 32 + srw) * KD + sc;
  const size_t b1 = b0 + (size_t)16 * KD;
  const size_t a0 = (size_t)(m0 + w * 16 + srw) * KD + sc;

  unsigned short* A0 = u.st.Ah;
  unsigned short* A1 = u.st.Ah + 64 * 32;
  unsigned short* B0 = u.st.Bh;
  unsigned short* B1 = u.st.Bh + 128 * 32;

  const int fm = lane & 15, fq = (lane >> 4) * 8;
  const int lB0 = (w * 32) * 32, lB1 = (w * 32 + 16) * 32;
  const int lA0 = (w * 16) * 32;

  auto stage = [&](int kk, unsigned short* A, unsigned short* B) {
    GLL16(Ahg + a0 + kk, A + lA0);
    GLL16(Bhg + b0 + kk, B + lB0);
    GLL16(Bhg + b1 + kk, B + lB1);
  };
  auto compute = [&](const unsigned short* A, const unsigned short* B) {
    bf16x8 ah[2], bh[4];
#pragma unroll
    for (int i = 0; i < 2; i++)
      ah[i] = *(const bf16x8*)&A[(wm + i * 16 + fm) * 32 + fq];
#pragma unroll
    for (int j = 0; j < 4; j++)
      bh[j] = *(const bf16x8*)&B[(wn + j * 16 + fm) * 32 + fq];
#pragma unroll
    for (int i = 0; i < 2; i++)
#pragma unroll
      for (int j = 0; j < 4; j++)
        acc[i][j] = MFMA(ah[i], bh[j], acc[i][j]);
  };

  stage(0, A0, B0);
  __syncthreads();
#pragma unroll
  for (int k0 = 0; k0 < KD; k0 += 64) {
    if (k0 + 32 < KD) stage(k0 + 32, A1, B1);
    compute(A0, B0);
    __syncthreads();
    if (k0 + 64 < KD) stage(k0 + 64, A0, B0);
    compute(A1, B1);
    __syncthreads();
  }
  // final in-loop barrier guarantees all frag reads done before tile reuse

  // write acc+bias into transpose tile: tile[t_local][e_local]
  const int quad = lane >> 4;
#pragma unroll
  for (int i = 0; i < 2; i++)
#pragma unroll
    for (int j = 0; j < 4; j++) {
      int ln = wn + j * 16 + fm;
      float bv = bias[n0 + ln];
#pragma unroll
      for (int r = 0; r < 4; r++) {
        int lm = wm + i * 16 + quad * 4 + r;
        u.tile[lm][ln] = acc[i][j][r] + bv;
      }
    }
  __syncthreads();

  // out[b,e,t] = relu(tile[t][e] * x[b,e,t]); coalesced along t
  const int bb = m0 >> 11, t0 = m0 & 2047;
  const int tt = tid & 63, e0w = tid >> 6;
#pragma unroll
  for (int k = 0; k < 32; k++) {
    int ee = e0w + k * 4;
    size_t o = ((size_t)bb * 512 + n0 + ee) * 2048 + t0 + tt;
    float v = u.tile[tt][ee] * x[o];
    out[o] = fmaxf(v, 0.f);
  }
}

// ---------------------------------------------------------------------------
// K2: local attention, barrier-free (R9 structure, harness-verified).
#define PSTR 200  // P row stride (bf16)
__global__ __launch_bounds__(256, 4) void k_attention(
    const unsigned short* __restrict__ Qs, const unsigned short* __restrict__ Kks,
    const unsigned short* __restrict__ VvT, unsigned short* __restrict__ ctx_hi) {
  __shared__ __align__(16) unsigned short P_s[64 * PSTR];  // 25.6 KB

  const int tid = threadIdx.x, lane = tid & 63, w = tid >> 6;
  const int q0 = blockIdx.x * 64;
  const int bh = blockIdx.y;
  const int j0 = q0 - 64;                    // window base key
  const size_t base = (size_t)bh * 2048 * 64;
  const int fm = lane & 15, quad = lane >> 4;

  // Q A-fragments for this wave's 16 rows (pre-scaled by 1/8 in QKV epilogue)
  bf16x8 aq[2];
  {
    const size_t qb = base + (size_t)(q0 + w * 16 + fm) * 64 + quad * 8;
#pragma unroll
    for (int ks = 0; ks < 2; ks++)
      aq[ks] = *(const bf16x8*)&Qs[qb + ks * 32];
  }

  // S = Q @ K^T over 10 key tiles; covers this wave's valid window AND the
  // P columns PV reads, so skipped/masked tiles give P=0.
  const int ct0 = (w >> 1) * 2;
  f32x4 sa[10];
#pragma unroll
  for (int u2 = 0; u2 < 10; u2++) sa[u2] = (f32x4){0.f, 0.f, 0.f, 0.f};
  __builtin_amdgcn_s_setprio(1);
#pragma unroll
  for (int u2 = 0; u2 < 10; u2++) {
    int jr = j0 + (ct0 + u2) * 16 + fm;
    jr = jr < 0 ? 0 : (jr > 2047 ? 2047 : jr);     // clamp: finite, masked below
    const unsigned short* kp = &Kks[base + (size_t)jr * 64 + quad * 8];
#pragma unroll
    for (int ks = 0; ks < 2; ks++) {
      bf16x8 bk = *(const bf16x8*)&kp[ks * 32];
      sa[u2] = MFMA(aq[ks], bk, sa[u2]);
    }
  }
  __builtin_amdgcn_s_setprio(0);

  // mask (REPLACE) + per-row max
  float rm[4], rs[4], inv[4];
#pragma unroll
  for (int r = 0; r < 4; r++) rm[r] = -1e30f;
#pragma unroll
  for (int u2 = 0; u2 < 10; u2++) {
    int jj = (ct0 + u2) * 16 + fm;               // block-local key col
    int jg = j0 + jj;
    bool jok = (jg >= 0) && (jg < 2048);
#pragma unroll
    for (int r = 0; r < 4; r++) {
      int ii = w * 16 + quad * 4 + r;            // block-local query row
      bool ok = jok && (jj >= ii) && (jj <= ii + 128);
      float sv = ok ? sa[u2][r] : -1e30f;
      sa[u2][r] = sv;
      rm[r] = fmaxf(rm[r], sv);
    }
  }
#pragma unroll
  for (int off = 1; off < 16; off <<= 1)
#pragma unroll
    for (int r = 0; r < 4; r++) rm[r] = fmaxf(rm[r], __shfl_xor(rm[r], off));
#pragma unroll
  for (int r = 0; r < 4; r++) rs[r] = 0.f;
#pragma unroll
  for (int u2 = 0; u2 < 10; u2++)
#pragma unroll
    for (int r = 0; r < 4; r++) {
      float e = __expf(sa[u2][r] - rm[r]);
      sa[u2][r] = e;
      rs[r] += e;
    }
#pragma unroll
  for (int off = 1; off < 16; off <<= 1)
#pragma unroll
    for (int r = 0; r < 4; r++) rs[r] += __shfl_xor(rs[r], off);
#pragma unroll
  for (int r = 0; r < 4; r++) inv[r] = 1.0f / rs[r];

  // P (bf16) -> wave-private LDS slab; intra-wave: lgkmcnt(0) + sched fence.
#pragma unroll
  for (int u2 = 0; u2 < 10; u2++)
#pragma unroll
    for (int r = 0; r < 4; r++) {
      int row = w * 16 + quad * 4 + r;
      P_s[row * PSTR + (ct0 + u2) * 16 + fm] = f2bf(sa[u2][r] * inv[r]);
    }
  asm volatile("s_waitcnt lgkmcnt(0)" ::: "memory");
  __builtin_amdgcn_sched_barrier(0);

  // ctx = P @ V^T direct from global; 5 k-slots cover the wave's window.
  const int ks0 = w >> 1;
  f32x4 oa[4];
#pragma unroll
  for (int dt = 0; dt < 4; dt++) oa[dt] = (f32x4){0.f, 0.f, 0.f, 0.f};
  __builtin_amdgcn_s_setprio(1);
#pragma unroll
  for (int ku = 0; ku < 5; ku++) {
    int ks = ks0 + ku;
    bf16x8 ap = *(const bf16x8*)&P_s[(w * 16 + fm) * PSTR + ks * 32 + quad * 8];
    int j = j0 + ks * 32 + quad * 8;             // 8-aligned chunk
    j = (j < 0 || j > 2040) ? 0 : j;             // OOB chunk -> valid addr (P=0)
    const unsigned short* vp = &VvT[base + j];
#pragma unroll
    for (int dt = 0; dt < 4; dt++) {
      bf16x8 bv = *(const bf16x8*)&vp[(size_t)(dt * 16 + fm) * 2048];
      oa[dt] = MFMA(ap, bv, oa[dt]);
    }
  }
  __builtin_amdgcn_s_setprio(0);

  // write ctx bf16 [B*T, 512]
  const int bb = bh >> 3, h = bh & 7;
#pragma unroll
  for (int dt = 0; dt < 4; dt++)
#pragma unroll
    for (int r = 0; r < 4; r++) {
      int t = q0 + w * 16 + quad * 4 + r;
      int c = h * 64 + dt * 16 + fm;
      ctx_hi[((size_t)(bb * 2048 + t)) * 512 + c] = f2bf(oa[dt][r]);
    }
}

// ---------------------------------------------------------------------------
extern "C" void kernel_launch(void* const* d_in, const int* in_sizes, int n_in,
                              void* d_out, int out_size, void* d_ws, size_t ws_size,
                              hipStream_t stream) {
  const float* x = (const float*)d_in[0];
  const float* w_in = (const float*)d_in[1];
  const float* b_in = (const float*)d_in[2];
  const float* w_out = (const float*)d_in[3];
  const float* b_out = (const float*)d_in[4];
  float* out = (float*)d_out;

  uint8_t* ws = (uint8_t*)d_ws;
  unsigned short* xT_hi = (unsigned short*)(ws + 0);           // 4 MiB
  unsigned short* wih   = (unsigned short*)(ws + 8388608);     // 1.5 MiB
  unsigned short* woh   = (unsigned short*)(ws + 9961472);     // 0.5 MiB
  unsigned short* Qs    = (unsigned short*)(ws + 12582912);    // 4 MiB
  unsigned short* Kk    = (unsigned short*)(ws + 16777216);    // 4 MiB
  unsigned short* VvT   = (unsigned short*)(ws + 20971520);    // 4 MiB [B,H,64,T]
  unsigned short* ctxh  = (unsigned short*)(ws + 25165824);    // 4 MiB

  k_prep<<<dim3(32, 9, 2), 256, 0, stream>>>(x, w_in, w_out, xT_hi, wih, woh);
  k_gemm_qkv<<<384, 256, 0, stream>>>(xT_hi, wih, b_in, Qs, Kk, VvT);
  k_attention<<<dim3(32, 16), 256, 0, stream>>>(Qs, Kk, VvT, ctxh);
  k_gemm_out<<<256, 256, 0, stream>>>(ctxh, woh, b_out, x, out);
}